// Round 6
// baseline (278.687 us; speedup 1.0000x reference)
//
#include <hip/hip_runtime.h>

#define ROW_L 32000
#define NT    512            // 8 waves: wave = expert*2 + half
#define NV    (ROW_L / 4)    // 8000 float4 per row
#define HV    4000           // float4 per half-row
#define UF    8              // float4 per load batch per wave (single-buffered)

typedef float f32x4 __attribute__((ext_vector_type(4)));

__global__ __launch_bounds__(NT, 8) void oracle_best_expert_kernel(
    const int* __restrict__ labels,
    const float* __restrict__ g0,
    const float* __restrict__ g1,
    const float* __restrict__ g2,
    const float* __restrict__ g3,
    float* __restrict__ out)
{
    const int b = blockIdx.x;
    const size_t row = (size_t)b * ROW_L;
    const float* __restrict__ p0 = g0 + row;
    const float* __restrict__ p1 = g1 + row;
    const float* __restrict__ p2 = g2 + row;
    const float* __restrict__ p3 = g3 + row;

    const int tid  = threadIdx.x;
    const int wave = tid >> 6;        // 0..7
    const int lane = tid & 63;
    const int e    = wave >> 1;       // this wave's expert
    const int h    = wave & 1;        // this wave's half-row
    const int r0   = h * HV;          // float4 region base

    __shared__ float s_max[8];
    __shared__ int   s_idx[8];
    __shared__ int   s_fix;           // corrective expert (-1 = spec held)

    const float* __restrict__ pw = (e == 0) ? p0 :
                                   (e == 1) ? p1 :
                                   (e == 2) ? p2 : p3;
    const f32x4* __restrict__ q  = (const f32x4*)pw;
    f32x4* __restrict__       qo = (f32x4*)(out + row);

    // Label logits -> conf_best (speculative best expert; first-max rule).
    const int lab = labels[b];
    const float c0 = p0[lab], c1 = p1[lab], c2 = p2[lab], c3 = p3[lab];
    int cb = 0; float bm = c0;
    if (c1 > bm) { bm = c1; cb = 1; }
    if (c2 > bm) { bm = c2; cb = 2; }
    if (c3 > bm) { bm = c3; cb = 3; }
    const bool do_store = (e == cb);             // wave-uniform

    // Fused scan (+ speculative copy) of this wave's half-row.
    // Single-buffered UF-deep batches: issue 8 loads back-to-back, then
    // consume in load order (compiler emits incremental vmcnt waits).
    // Lane indices strictly increase -> strict '>' keeps the FIRST max.
    float m  = -__builtin_inff();
    int   mi = 0;

    f32x4 v[UF];
#pragma unroll 1
    for (int k = 0; k < 7; ++k) {
        const int base = r0 + k * (UF * 64) + lane;
#pragma unroll
        for (int u = 0; u < UF; ++u) v[u] = q[base + u * 64];
        __builtin_amdgcn_sched_barrier(0);
#pragma unroll
        for (int u = 0; u < UF; ++u) {
            const f32x4 t = v[u];
            const int fi = base + u * 64;
            const int bi = fi * 4;
            if (t.x > m) { m = t.x; mi = bi + 0; }
            if (t.y > m) { m = t.y; mi = bi + 1; }
            if (t.z > m) { m = t.z; mi = bi + 2; }
            if (t.w > m) { m = t.w; mi = bi + 3; }
            if (do_store) qo[fi] = t;
        }
    }
    {   // tail: 416 float4 = 6 full lane-rounds + 32
        const int base = r0 + 7 * (UF * 64) + lane;   // r0 + 3584 + lane
#pragma unroll
        for (int u = 0; u < 6; ++u) v[u] = q[base + u * 64];
        __builtin_amdgcn_sched_barrier(0);
#pragma unroll
        for (int u = 0; u < 6; ++u) {
            const f32x4 t = v[u];
            const int fi = base + u * 64;
            const int bi = fi * 4;
            if (t.x > m) { m = t.x; mi = bi + 0; }
            if (t.y > m) { m = t.y; mi = bi + 1; }
            if (t.z > m) { m = t.z; mi = bi + 2; }
            if (t.w > m) { m = t.w; mi = bi + 3; }
            if (do_store) qo[fi] = t;
        }
        if (lane < 32) {
            const int fi = r0 + 3968 + lane;
            const f32x4 t = q[fi];
            const int bi = fi * 4;
            if (t.x > m) { m = t.x; mi = bi + 0; }
            if (t.y > m) { m = t.y; mi = bi + 1; }
            if (t.z > m) { m = t.z; mi = bi + 2; }
            if (t.w > m) { m = t.w; mi = bi + 3; }
            if (do_store) qo[fi] = t;
        }
    }

    // 64-lane reduce; equal value -> smaller index (first occurrence).
#pragma unroll
    for (int off = 32; off >= 1; off >>= 1) {
        const float ov = __shfl_down(m, off, 64);
        const int   oi = __shfl_down(mi, off, 64);
        if (ov > m || (ov == m && oi < mi)) { m = ov; mi = oi; }
    }
    if (lane == 0) { s_max[wave] = m; s_idx[wave] = mi; }
    __syncthreads();

    // Resolve: combine halves (half1 indices all larger -> '>' keeps first
    // max), then first correct expert, else conf_best (already written).
    if (tid == 0) {
        int best = -1;
#pragma unroll
        for (int ee = 0; ee < 4; ++ee) {
            const int ix = (s_max[2 * ee + 1] > s_max[2 * ee])
                               ? s_idx[2 * ee + 1] : s_idx[2 * ee];
            if (best < 0 && ix == lab) best = ee;
        }
        if (best < 0) best = cb;
        s_fix = (best == cb) ? -1 : best;
    }
    __syncthreads();

    // Rare correction (~0.01% of rows): overwrite with the true winner.
    const int fx = s_fix;
    if (fx >= 0) {
        const f32x4* __restrict__ src = (const f32x4*)((fx == 0) ? p0 :
                                                       (fx == 1) ? p1 :
                                                       (fx == 2) ? p2 : p3);
        for (int i = tid; i < NV; i += NT) qo[i] = src[i];
    }
}

extern "C" void kernel_launch(void* const* d_in, const int* in_sizes, int n_in,
                              void* d_out, int out_size, void* d_ws, size_t ws_size,
                              hipStream_t stream) {
    const int*   labels = (const int*)d_in[0];
    const float* g0     = (const float*)d_in[1];
    const float* g1     = (const float*)d_in[2];
    const float* g2     = (const float*)d_in[3];
    const float* g3     = (const float*)d_in[4];
    float*       out    = (float*)d_out;

    const int B = in_sizes[0];  // 2048 rows
    oracle_best_expert_kernel<<<B, NT, 0, stream>>>(labels, g0, g1, g2, g3, out);
}

// Round 7
// 267.154 us; speedup vs baseline: 1.0432x; 1.0432x over previous
//
#include <hip/hip_runtime.h>

#define ROW_L 32000
#define NT    512            // 8 waves: wave = expert*2 + half
#define NV    (ROW_L / 4)    // 8000 float4 per row
#define HV    4000           // float4 per half-row
#define UF    4              // float4 per load batch per wave (ping-pong)

typedef float f32x4 __attribute__((ext_vector_type(4)));

// Batch of UF coalesced nontemporal float4 loads (streamed once, no reuse).
#define LOADB(dst, kk) do {                                                  \
    const int base_ = r0 + (kk) * (UF * 64) + lane;                          \
    _Pragma("unroll")                                                        \
    for (int u = 0; u < UF; ++u)                                             \
        dst[u] = __builtin_nontemporal_load(&q[base_ + u * 64]);             \
    __builtin_amdgcn_sched_barrier(0);                                       \
} while (0)

// Consume a batch: running first-max argmax; conf_best expert's waves also
// stream the values to out (speculative fused copy, zero extra reads).
#define CONSUME(src, kk) do {                                                \
    const int base_ = r0 + (kk) * (UF * 64) + lane;                          \
    _Pragma("unroll")                                                        \
    for (int u = 0; u < UF; ++u) {                                           \
        const f32x4 v = src[u];                                              \
        const int fi = base_ + u * 64;                                       \
        const int bi = fi * 4;                                               \
        if (v.x > m) { m = v.x; mi = bi + 0; }                               \
        if (v.y > m) { m = v.y; mi = bi + 1; }                               \
        if (v.z > m) { m = v.z; mi = bi + 2; }                               \
        if (v.w > m) { m = v.w; mi = bi + 3; }                               \
        if (do_store) qo[fi] = v;                                            \
    }                                                                        \
} while (0)

__global__ __launch_bounds__(NT, 8) void oracle_best_expert_kernel(
    const int* __restrict__ labels,
    const float* __restrict__ g0,
    const float* __restrict__ g1,
    const float* __restrict__ g2,
    const float* __restrict__ g3,
    float* __restrict__ out)
{
    const int b = blockIdx.x;
    const size_t row = (size_t)b * ROW_L;
    const float* __restrict__ p0 = g0 + row;
    const float* __restrict__ p1 = g1 + row;
    const float* __restrict__ p2 = g2 + row;
    const float* __restrict__ p3 = g3 + row;

    const int tid  = threadIdx.x;
    const int wave = tid >> 6;        // 0..7
    const int lane = tid & 63;
    const int e    = wave >> 1;       // this wave's expert
    const int h    = wave & 1;        // this wave's half-row
    const int r0   = h * HV;          // float4 region base

    __shared__ float s_max[8];
    __shared__ int   s_idx[8];
    __shared__ int   s_fix;           // corrective expert (-1 = spec held)

    const float* __restrict__ pw = (e == 0) ? p0 :
                                   (e == 1) ? p1 :
                                   (e == 2) ? p2 : p3;
    const f32x4* __restrict__ q  = (const f32x4*)pw;
    f32x4* __restrict__       qo = (f32x4*)(out + row);

    // Label logits -> conf_best (speculative best expert; first-max rule).
    const int lab = labels[b];
    const float c0 = p0[lab], c1 = p1[lab], c2 = p2[lab], c3 = p3[lab];
    int cb = 0; float bm = c0;
    if (c1 > bm) { bm = c1; cb = 1; }
    if (c2 > bm) { bm = c2; cb = 2; }
    if (c3 > bm) { bm = c3; cb = 3; }
    const bool do_store = (e == cb);             // wave-uniform

    // Fused scan (+ speculative copy), UF=4 ping-pong double buffer.
    // Lane indices strictly increase -> strict '>' keeps the FIRST max.
    // 4000 float4 per half-row = 15 batches of 256 + 160 tail.
    float m  = -__builtin_inff();
    int   mi = 0;

    f32x4 Abuf[UF], Bbuf[UF];
    LOADB(Abuf, 0);
#pragma unroll 1
    for (int k = 0; k < 14; k += 2) {
        LOADB(Bbuf, k + 1);
        CONSUME(Abuf, k);
        LOADB(Abuf, k + 2);
        CONSUME(Bbuf, k + 1);
    }
    CONSUME(Abuf, 14);
    {   // tail: 160 float4 = 2 full lane-rounds + 32
        const int base = r0 + 15 * (UF * 64) + lane;   // r0 + 3840 + lane
        f32x4 T[2];
#pragma unroll
        for (int u = 0; u < 2; ++u)
            T[u] = __builtin_nontemporal_load(&q[base + u * 64]);
#pragma unroll
        for (int u = 0; u < 2; ++u) {
            const f32x4 v = T[u];
            const int fi = base + u * 64;
            const int bi = fi * 4;
            if (v.x > m) { m = v.x; mi = bi + 0; }
            if (v.y > m) { m = v.y; mi = bi + 1; }
            if (v.z > m) { m = v.z; mi = bi + 2; }
            if (v.w > m) { m = v.w; mi = bi + 3; }
            if (do_store) qo[fi] = v;
        }
        if (lane < 32) {
            const int fi = r0 + 3968 + lane;
            const f32x4 v = __builtin_nontemporal_load(&q[fi]);
            const int bi = fi * 4;
            if (v.x > m) { m = v.x; mi = bi + 0; }
            if (v.y > m) { m = v.y; mi = bi + 1; }
            if (v.z > m) { m = v.z; mi = bi + 2; }
            if (v.w > m) { m = v.w; mi = bi + 3; }
            if (do_store) qo[fi] = v;
        }
    }

    // 64-lane reduce; equal value -> smaller index (first occurrence).
#pragma unroll
    for (int off = 32; off >= 1; off >>= 1) {
        const float ov = __shfl_down(m, off, 64);
        const int   oi = __shfl_down(mi, off, 64);
        if (ov > m || (ov == m && oi < mi)) { m = ov; mi = oi; }
    }
    if (lane == 0) { s_max[wave] = m; s_idx[wave] = mi; }
    __syncthreads();

    // Resolve: combine halves (half1 indices all larger -> '>' keeps first
    // max), then first correct expert, else conf_best (already written).
    if (tid == 0) {
        int best = -1;
#pragma unroll
        for (int ee = 0; ee < 4; ++ee) {
            const int ix = (s_max[2 * ee + 1] > s_max[2 * ee])
                               ? s_idx[2 * ee + 1] : s_idx[2 * ee];
            if (best < 0 && ix == lab) best = ee;
        }
        if (best < 0) best = cb;
        s_fix = (best == cb) ? -1 : best;
    }
    __syncthreads();

    // Rare correction (~0.01% of rows): overwrite with the true winner.
    const int fx = s_fix;
    if (fx >= 0) {
        const f32x4* __restrict__ src = (const f32x4*)((fx == 0) ? p0 :
                                                       (fx == 1) ? p1 :
                                                       (fx == 2) ? p2 : p3);
        for (int i = tid; i < NV; i += NT) qo[i] = src[i];
    }
}

extern "C" void kernel_launch(void* const* d_in, const int* in_sizes, int n_in,
                              void* d_out, int out_size, void* d_ws, size_t ws_size,
                              hipStream_t stream) {
    const int*   labels = (const int*)d_in[0];
    const float* g0     = (const float*)d_in[1];
    const float* g1     = (const float*)d_in[2];
    const float* g2     = (const float*)d_in[3];
    const float* g3     = (const float*)d_in[4];
    float*       out    = (float*)d_out;

    const int B = in_sizes[0];  // 2048 rows
    oracle_best_expert_kernel<<<B, NT, 0, stream>>>(labels, g0, g1, g2, g3, out);
}